// Round 3
// baseline (2599.422 us; speedup 1.0000x reference)
//
#include <hip/hip_runtime.h>
#include <hip/hip_bf16.h>
#include <stdint.h>
#include <stddef.h>

using bf16 = __hip_bfloat16;
typedef short s16x8 __attribute__((ext_vector_type(8)));   // 8 bf16 = one MFMA frag (4 VGPRs)
typedef float f32x4 __attribute__((ext_vector_type(4)));

#define MFMA16(a, b, c) __builtin_amdgcn_mfma_f32_16x16x32_bf16((a), (b), (c), 0, 0, 0)

typedef __attribute__((address_space(1))) void gvoid;
typedef __attribute__((address_space(3))) void lvoid;
// global -> LDS direct copy, 16B per lane; LDS dest = wave-uniform base + lane*16
#define GLL16(gp, lp) __builtin_amdgcn_global_load_lds((gvoid*)(void*)(gp), (lvoid*)(lp), 16, 0, 0)

__device__ __forceinline__ short f2bf(float x) {
    bf16 h = __float2bfloat16(x);
    return __builtin_bit_cast(short, h);
}

// f32 -> bf16 elementwise, n % 1024 == 0, grid*block*4 == n
__global__ void cvt_bf16(const float* __restrict__ in, bf16* __restrict__ out, int n) {
    int i = (blockIdx.x * blockDim.x + threadIdx.x) * 4;
    if (i < n) {
        float4 v = *(const float4*)(in + i);
        out[i + 0] = __float2bfloat16(v.x);
        out[i + 1] = __float2bfloat16(v.y);
        out[i + 2] = __float2bfloat16(v.z);
        out[i + 3] = __float2bfloat16(v.w);
    }
}

// ---------------------------------------------------------------------------
// C[om(m)][n] = bias[n] + sum_k A[m][k] * Bt[n][k]     (K = N = 1024)
// A_F32: A is f32, staged via register convert + ds_write_b128 (XOR-swizzled
//        chunk layout identical to the GLL16 path). Else A is bf16 via GLL16.
// OUT_F32: store f32 (+f32 bias) else bf16.  bias always f32.
// REMAP: 0 none; 1 m=b*512+t -> t*64+b ; 2 m=t*64+b -> b*512+t
// 128x128 tile, BK=64, 4 waves each 64x64 (m97-verified structure).
// ---------------------------------------------------------------------------
template<bool A_F32, bool OUT_F32, int REMAP>
__global__ __launch_bounds__(256) void gemm_bt(
    const void* __restrict__ Ap, const bf16* __restrict__ Bt,
    const float* __restrict__ bias, void* __restrict__ Cp)
{
    __shared__ __align__(16) bf16 lA[128 * 64];
    __shared__ __align__(16) bf16 lB[128 * 64];

    const int tid  = threadIdx.x;
    const int lane = tid & 63, wv = tid >> 6;
    const int wm = wv & 1, wn = wv >> 1;
    const int quad = lane >> 4, l16 = lane & 15;
    const int m0 = blockIdx.x * 128, n0 = blockIdx.y * 128;

    // GLL16 staging pattern: inst q covers rows q*8..q*8+7,
    // lane -> (row q*8+sr, source chunk (lane&7)^sr at LDS chunk lane&7)
    const int sr = lane >> 3;
    const int sc = ((lane & 7) ^ sr) * 8;   // element offset of swizzled 16B chunk

    // f32-A staging pattern: thread -> row tid>>1, source chunks (tid&1)*4..+3,
    // LDS chunk = c ^ (row&7)  (same final layout as the GLL16 path)
    const int ar = tid >> 1;
    const int ah = tid & 1;

    f32x4 acc[4][4] = {};

    for (int ko = 0; ko < 1024; ko += 64) {
        if constexpr (A_F32) {
            const float* Af = (const float*)Ap;
#pragma unroll
            for (int i = 0; i < 4; ++i) {
                const int c = ah * 4 + i;                    // source chunk 0..7
                const float* src = Af + (size_t)(m0 + ar) * 1024 + ko + c * 8;
                float4 v0 = *(const float4*)(src);
                float4 v1 = *(const float4*)(src + 4);
                s16x8 w;
                w[0] = f2bf(v0.x); w[1] = f2bf(v0.y); w[2] = f2bf(v0.z); w[3] = f2bf(v0.w);
                w[4] = f2bf(v1.x); w[5] = f2bf(v1.y); w[6] = f2bf(v1.z); w[7] = f2bf(v1.w);
                *(s16x8*)((char*)lA + ar * 128 + ((c ^ (ar & 7)) << 4)) = w;
            }
#pragma unroll
            for (int qi = 0; qi < 4; ++qi) {
                const int q = wv * 4 + qi;
                GLL16(Bt + (size_t)(n0 + q * 8 + sr) * 1024 + ko + sc, (char*)lB + q * 1024);
            }
        } else {
            const bf16* Ab = (const bf16*)Ap;
#pragma unroll
            for (int qi = 0; qi < 4; ++qi) {
                const int q = wv * 4 + qi;
                GLL16(Ab + (size_t)(m0 + q * 8 + sr) * 1024 + ko + sc, (char*)lA + q * 1024);
                GLL16(Bt + (size_t)(n0 + q * 8 + sr) * 1024 + ko + sc, (char*)lB + q * 1024);
            }
        }
        __syncthreads();   // drains vmcnt + lgkmcnt before s_barrier
#pragma unroll
        for (int kc = 0; kc < 2; ++kc) {
            s16x8 af[4], bg[4];
#pragma unroll
            for (int mt = 0; mt < 4; ++mt) {
                const int r = 64 * wm + 16 * mt + l16;
                const int c = kc * 4 + quad;
                af[mt] = *(const s16x8*)((const char*)lA + r * 128 + ((c ^ (r & 7)) * 16));
            }
#pragma unroll
            for (int nt = 0; nt < 4; ++nt) {
                const int r = 64 * wn + 16 * nt + l16;
                const int c = kc * 4 + quad;
                bg[nt] = *(const s16x8*)((const char*)lB + r * 128 + ((c ^ (r & 7)) * 16));
            }
#pragma unroll
            for (int mt = 0; mt < 4; ++mt)
#pragma unroll
                for (int nt = 0; nt < 4; ++nt)
                    acc[mt][nt] = MFMA16(af[mt], bg[nt], acc[mt][nt]);
        }
        __syncthreads();
    }

    float bv[4];
#pragma unroll
    for (int nt = 0; nt < 4; ++nt)
        bv[nt] = bias[n0 + 64 * wn + 16 * nt + l16];

    // D layout: row = quad*4 + reg, col = lane&15  (m89/m91-verified)
#pragma unroll
    for (int mt = 0; mt < 4; ++mt) {
#pragma unroll
        for (int r = 0; r < 4; ++r) {
            const int m = m0 + 64 * wm + 16 * mt + 4 * quad + r;
            int om = m;
            if constexpr (REMAP == 1)      om = ((m & 511) << 6) | (m >> 9); // b*512+t -> t*64+b
            else if constexpr (REMAP == 2) om = ((m & 63) << 9) | (m >> 6);  // t*64+b -> b*512+t
#pragma unroll
            for (int nt = 0; nt < 4; ++nt) {
                const int n = n0 + 64 * wn + 16 * nt + l16;
                const float val = acc[mt][nt][r] + bv[nt];
                if constexpr (OUT_F32) ((float*)Cp)[(size_t)om * 1024 + n] = val;
                else ((bf16*)Cp)[(size_t)om * 1024 + n] = __float2bfloat16(val);
            }
        }
    }
}

// ---------------------------------------------------------------------------
// One recurrence step:  A[t] = U[t] + A[t-1] @ Waa^T   (in place in UA, bf16)
// UA layout: [T=512][B=64][1024].  A[0] = U[0] already correct.
// Launched 511 times; kernel boundaries provide ordering + visibility.
// Block b: bi=b&3 -> batch rows 16*bi..+15; nj=b>>2 -> act cols 16*nj..+15.
// ---------------------------------------------------------------------------
__global__ __launch_bounds__(64, 1) void scan_step(
    const bf16* __restrict__ Waa, bf16* __restrict__ UA, int t)
{
    const int lane = threadIdx.x;
    const int quad = lane >> 4, l16 = lane & 15;
    const int bi = blockIdx.x & 3, nj = blockIdx.x >> 2;

    const bf16* arow = UA  + ((size_t)((t - 1) * 64 + 16 * bi + l16)) * 1024;
    const bf16* wrow = Waa + ((size_t)(16 * nj + l16)) * 1024;

    // acc init from U[t] slice (D layout: row = 4*quad+rr, col = l16)
    const bf16* urow = UA + ((size_t)(t * 64 + 16 * bi + 4 * quad)) * 1024 + 16 * nj + l16;
    f32x4 acc;
#pragma unroll
    for (int rr = 0; rr < 4; ++rr)
        acc[rr] = __bfloat162float(urow[(size_t)rr * 1024]);

    s16x8 av[32], wf[32];
#pragma unroll
    for (int kc = 0; kc < 32; ++kc) {
        av[kc] = *(const s16x8*)(arow + kc * 32 + quad * 8);
        wf[kc] = *(const s16x8*)(wrow + kc * 32 + quad * 8);
    }
#pragma unroll
    for (int kc = 0; kc < 32; ++kc)
        acc = MFMA16(av[kc], wf[kc], acc);

    bf16* drow = UA + ((size_t)(t * 64 + 16 * bi + 4 * quad)) * 1024 + 16 * nj + l16;
#pragma unroll
    for (int rr = 0; rr < 4; ++rr)
        drow[(size_t)rr * 1024] = __float2bfloat16(acc[rr]);
}

// ---------------------------------------------------------------------------
extern "C" void kernel_launch(void* const* d_in, const int* in_sizes, int n_in,
                              void* d_out, int out_size, void* d_ws, size_t ws_size,
                              hipStream_t stream) {
    const float* X   = (const float*)d_in[0];   // [64,512,1024] f32
    const float* Wax = (const float*)d_in[1];   // [1024,1024]   f32
    const float* Waa = (const float*)d_in[2];   // [1024,1024]   f32
    const float* ba  = (const float*)d_in[3];   // [1024]        f32
    const float* Wy  = (const float*)d_in[4];   // [1024,1024]   f32
    const float* by  = (const float*)d_in[5];   // [1024]        f32

    char* ws = (char*)d_ws;
    bf16* UA   = (bf16*)ws;                                   // 64 MB: [512][64][1024]
    bf16* Waxb = (bf16*)(ws + 67108864);                      // 2 MB
    bf16* Waab = (bf16*)(ws + 67108864 + 2097152);            // 2 MB
    bf16* Wyb  = (bf16*)(ws + 67108864 + 2 * 2097152);        // 2 MB  (total 70 MB)

    const int NW = 1024 * 1024;
    cvt_bf16<<<dim3(NW / 1024), dim3(256), 0, stream>>>(Wax, Waxb, NW);
    cvt_bf16<<<dim3(NW / 1024), dim3(256), 0, stream>>>(Waa, Waab, NW);
    cvt_bf16<<<dim3(NW / 1024), dim3(256), 0, stream>>>(Wy,  Wyb,  NW);

    dim3 grid(256, 8), blk(256);
    // Phase A: U = X @ Wax^T + ba   (f32 A-operand, rows b*512+t -> t*64+b, bf16 out)
    gemm_bt<true, false, 1><<<grid, blk, 0, stream>>>(X, Waxb, ba, UA);
    // Phase B: sequential recurrence, one launch per step
    for (int t = 1; t < 512; ++t)
        scan_step<<<dim3(256), dim3(64), 0, stream>>>(Waab, UA, t);
    // Phase C: Y = A @ Wy^T + by    (rows t*64+b -> b*512+t, f32 out to d_out)
    gemm_bt<false, true, 2><<<grid, blk, 0, stream>>>(UA, Wyb, by, (float*)d_out);
}